// Round 6
// baseline (198.143 us; speedup 1.0000x reference)
//
#include <hip/hip_runtime.h>

#define BB   16
#define CINC 64
#define COUTC 64
#define HH   128
#define WW   128

typedef _Float16 f16x8 __attribute__((ext_vector_type(8)));
typedef _Float16 f16x4 __attribute__((ext_vector_type(4)));
typedef float f32x4 __attribute__((ext_vector_type(4)));

typedef const __attribute__((address_space(1))) void* gas_ptr;
typedef __attribute__((address_space(3))) void* las_ptr;

__device__ __forceinline__ float lrelu(float v) {
    return fmaxf(v, 0.f) + 0.01f * fminf(v, 0.f);
}

__device__ __forceinline__ void gload_lds16(const void* g, void* l) {
    __builtin_amdgcn_global_load_lds((gas_ptr)g, (las_ptr)l, 16, 0, 0);
}

// ============ Kernel 1: prep = xsplit (blocks 0..4095) + hypernet (4096..4159) ============
// xsplit: x[b][ci][y][x] f32 -> xt[b][y][x]{256B: 16 slots of 16B}, slot s =
// (chunk<<3)|(plane<<2)|g holding f16x8 of ci = chunk*32+g*8.. (hi or lo plane).
// hyper: wf fragment array for MFMA B-operand + 1KB zero page.
__global__ __launch_bounds__(256)
void prep_kernel(const float* __restrict__ x,
                 const float* __restrict__ h,
                 const float* __restrict__ fc_w,
                 const float* __restrict__ fc_b,
                 const float* __restrict__ w1,
                 const float* __restrict__ b1,
                 const float* __restrict__ w2,
                 const float* __restrict__ b2,
                 const float* __restrict__ w3,
                 const float* __restrict__ b3,
                 _Float16* __restrict__ wf,
                 float* __restrict__ zp,
                 _Float16* __restrict__ xt) {
    __shared__ __align__(16) char smem[16384];
    const int bid = blockIdx.x;
    const int t   = threadIdx.x;

    if (bid < 4096) {
        // ---------------- xsplit part ----------------
        char* lt = smem;
        const int xh = bid & 1;
        const int y  = (bid >> 1) & 127;
        const int b  = bid >> 8;
        const int cig = t >> 4;           // 0..15 -> 4 consecutive ci
        const int pxq = t & 15;           // 0..15 -> 4 consecutive pixels
        const int chunk = cig >> 3;
        const int g     = (cig >> 1) & 3;
        const int jh    = cig & 1;
        const int ci0   = chunk * 32 + g * 8 + jh * 4;
        const int x0    = xh * 64;

        f32x4 xv[4];
        #pragma unroll
        for (int r = 0; r < 4; ++r)
            xv[r] = *(const f32x4*)(x + (((size_t)(b * CINC + ci0 + r) * HH + y) * WW + x0 + pxq * 4));

        const int off_hi = (chunk << 7) + (g << 4) + (jh << 3);
        #pragma unroll
        for (int ii = 0; ii < 4; ++ii) {
            int px = pxq * 4 + ii;
            f16x4 hv, lv;
            #pragma unroll
            for (int r = 0; r < 4; ++r) {
                float v = xv[r][ii];
                _Float16 hh = (_Float16)v;
                hv[r] = hh;
                lv[r] = (_Float16)(v - (float)hh);
            }
            int sw = (px & 7) << 4;
            *(f16x4*)(lt + (px << 8) + ((off_hi)      ^ sw)) = hv;
            *(f16x4*)(lt + (px << 8) + ((off_hi + 64) ^ sw)) = lv;
        }
        __syncthreads();

        char* dst = (char*)xt + (((size_t)(b * HH + y) * WW + x0) << 8);
        #pragma unroll
        for (int r = 0; r < 4; ++r) {
            int lu = r * 256 + t;
            int px = lu >> 4;
            int sl = lu & 15;
            f16x8 v = *(const f16x8*)(lt + (px << 8) + ((sl ^ (px & 7)) << 4));
            *(f16x8*)(dst + (size_t)lu * 16) = v;
        }
    } else {
        // ---------------- hypernet part ----------------
        float* hs  = (float*)smem;        // 8
        float* k0s = hs + 8;              // 144
        float* k1s = k0s + 144;           // 288
        float* k2s = k1s + 288;           // 288
        const int j   = bid - 4096;       // 0..63
        const int b   = j & 15;
        const int cog = j >> 4;           // co group of 16

        if (t < 8) hs[t] = h[b * 8 + t];
        if (j == 0 && t < 64) *(f32x4*)((char*)zp + t * 16) = (f32x4){0.f, 0.f, 0.f, 0.f};
        __syncthreads();
        if (t < 144) {
            float a = fc_b[t];
            #pragma unroll
            for (int c = 0; c < 8; ++c) a += hs[c] * fc_w[t * 8 + c];
            k0s[t] = lrelu(a);
        }
        __syncthreads();
        for (int i = t; i < 288; i += 256) {
            int o = i / 9, tap = i % 9;
            float a = b1[o];
            #pragma unroll
            for (int c = 0; c < 16; ++c) a += w1[o * 16 + c] * k0s[c * 9 + tap];
            k1s[i] = lrelu(a);
        }
        __syncthreads();
        for (int i = t; i < 288; i += 256) {
            int o = i / 9, tap = i % 9;
            float a = b2[o];
            #pragma unroll
            for (int c = 0; c < 32; ++c) a += w2[o * 32 + c] * k1s[c * 9 + tap];
            k2s[i] = lrelu(a);
        }
        __syncthreads();

        const int co = cog * 16 + (t >> 4);
        const int ci_base = (t & 15) * 4;
        #pragma unroll 1
        for (int cq = 0; cq < 4; ++cq) {
            int ci = ci_base + cq;
            int o = co * CINC + ci;
            float wrow[32];
            #pragma unroll
            for (int c = 0; c < 32; ++c) wrow[c] = w3[o * 32 + c];
            float bb3 = b3[o];
            int chunk = ci >> 5;
            int g     = (ci >> 3) & 3;
            int jj    = ci & 7;
            int lane  = (g << 4) | (co & 15);
            #pragma unroll
            for (int tap = 0; tap < 9; ++tap) {
                float a = bb3;
                #pragma unroll
                for (int c = 0; c < 32; ++c) a += wrow[c] * k2s[c * 9 + tap];
                size_t frag = ((size_t)(b * 9 + tap) * 2 + chunk) * 4 + (co >> 4);
                wf[frag * 512 + lane * 8 + jj] = (_Float16)a;
            }
        }
    }
}

// ============ Kernel 2: MFMA conv, double-buffered global_load_lds pipeline ============
// Block: 256 thr (4 waves), tile 16x16 px x all 64 co. 4 phases (chunk,plane),
// LDS ping-pong 2 x 20736B. stage(vc+1) issued BEFORE compute(vc): load latency
// hides under the 576-MFMA phase; barrier drain is then near-free.
__global__ __launch_bounds__(256, 3)
void conv_mfma3_kernel(const _Float16* __restrict__ xt,
                       const _Float16* __restrict__ wf,
                       const float* __restrict__ bias,
                       const float* __restrict__ zp,
                       float* __restrict__ out) {
    __shared__ __align__(16) char xs[2][324 * 64];   // 41472 B total

    const int b   = blockIdx.z;
    const int x0  = blockIdx.x * 16;
    const int y0  = blockIdx.y * 16;
    const int tid = threadIdx.x;
    const int lane = tid & 63;
    const int w    = tid >> 6;       // wave 0..3, owns rows w*4..w*4+3
    const int lc   = lane & 15;
    const int g    = lane >> 4;

    f32x4 acc[4][4];
    #pragma unroll
    for (int m = 0; m < 4; ++m)
        #pragma unroll
        for (int n = 0; n < 4; ++n)
            acc[m][n] = (f32x4){0.f, 0.f, 0.f, 0.f};

    const char* xtb = (const char*)xt;
    const char* zpb = (const char*)zp;
    const f16x8* wfb = (const f16x8*)wf;

    // ---- stage one (chunk,plane) quarter into dbuf via global_load_lds ----
    auto stage = [&](char* dbuf, int chunk, int plane) {
        const int cpo = (chunk << 7) + (plane << 6);
        #pragma unroll
        for (int i = 0; i < 5; ++i) {
            int ub = (i * 4 + w) << 6;         // wave-uniform unit base
            int u  = ub + lane;
            int p = u >> 2, s = u & 3;
            int srow = p / 18;
            int scol = p - srow * 18;
            int gy = y0 - 1 + srow;
            int gx = x0 - 1 + scol;
            const char* gp;
            if ((unsigned)gy < HH && (unsigned)gx < WW)
                gp = xtb + ((((size_t)b * HH + gy) * WW + gx) << 8) + cpo + (((s - p) & 3) << 4);
            else
                gp = zpb + ((u & 63) << 4);
            gload_lds16(gp, dbuf + (ub << 4));
        }
        if (tid < 16) {                        // tail units 1280..1295 (wave 0)
            int u = 1280 + tid;
            int p = u >> 2, s = u & 3;
            int srow = p / 18;
            int scol = p - srow * 18;
            int gy = y0 - 1 + srow;
            int gx = x0 - 1 + scol;
            const char* gp;
            if ((unsigned)gy < HH && (unsigned)gx < WW)
                gp = xtb + ((((size_t)b * HH + gy) * WW + gx) << 8) + cpo + (((s - p) & 3) << 4);
            else
                gp = zpb + ((u & 63) << 4);
            gload_lds16(gp, dbuf + 1280 * 16);
        }
    };

    // ---- compute one staged quarter (K=32), B-frag tap+1 prefetch ----
    auto compute = [&](const char* sbuf, int chunk) {
        size_t fb0 = ((size_t)(b * 9) * 2 + chunk) * 4;
        f16x8 Bc[4], Bn[4];
        #pragma unroll
        for (int n = 0; n < 4; ++n) Bc[n] = wfb[(fb0 + n) * 64 + lane];
        #pragma unroll 1
        for (int tap = 0; tap < 9; ++tap) {
            if (tap < 8) {
                size_t fb = ((size_t)(b * 9 + tap + 1) * 2 + chunk) * 4;
                #pragma unroll
                for (int n = 0; n < 4; ++n) Bn[n] = wfb[(fb + n) * 64 + lane];
            }
            int ky = tap / 3;
            int kx = tap - ky * 3;
            #pragma unroll
            for (int m = 0; m < 4; ++m) {
                int srow = (w << 2) + m + ky;
                int p = srow * 18 + lc + kx;
                f16x8 A = *(const f16x8*)(sbuf + (p << 6) + (((g + p) & 3) << 4));
                #pragma unroll
                for (int n = 0; n < 4; ++n)
                    acc[m][n] = __builtin_amdgcn_mfma_f32_16x16x32_f16(A, Bc[n], acc[m][n], 0, 0, 0);
            }
            #pragma unroll
            for (int n = 0; n < 4; ++n) Bc[n] = Bn[n];
        }
    };

    stage((char*)xs[0], 0, 0);
    __syncthreads();
    #pragma unroll
    for (int vc = 0; vc < 4; ++vc) {
        if (vc < 3) stage((char*)xs[(vc + 1) & 1], (vc + 1) >> 1, (vc + 1) & 1);
        compute((const char*)xs[vc & 1], vc >> 1);
        __syncthreads();
    }

    // ---- epilogue: bias + coalesced dwordx4 stores ----
    float bval[4];
    #pragma unroll
    for (int n = 0; n < 4; ++n) bval[n] = bias[n * 16 + lc];
    #pragma unroll
    for (int m = 0; m < 4; ++m) {
        int y  = y0 + (w << 2) + m;
        int xx = x0 + g * 4;
        #pragma unroll
        for (int n = 0; n < 4; ++n) {
            int co = n * 16 + lc;
            f32x4 r = acc[m][n];
            r += bval[n];
            *(f32x4*)(out + (((size_t)(b * COUTC + co) * HH + y) * WW + xx)) = r;
        }
    }
}

extern "C" void kernel_launch(void* const* d_in, const int* in_sizes, int n_in,
                              void* d_out, int out_size, void* d_ws, size_t ws_size,
                              hipStream_t stream) {
    const float* x    = (const float*)d_in[0];
    const float* h    = (const float*)d_in[1];
    const float* fc_w = (const float*)d_in[2];
    const float* fc_b = (const float*)d_in[3];
    const float* w1   = (const float*)d_in[4];
    const float* b1   = (const float*)d_in[5];
    const float* w2   = (const float*)d_in[6];
    const float* b2   = (const float*)d_in[7];
    const float* w3   = (const float*)d_in[8];
    const float* b3   = (const float*)d_in[9];
    const float* bias = (const float*)d_in[10];
    float* out = (float*)d_out;

    // ws layout: zp (1KB) | wf (1,179,648 B) | xt (67,108,864 B) -- total ~68.3 MB
    const size_t ZP_BYTES = 1024;
    const size_t WF_BYTES = (size_t)BB * 9 * 2 * 4 * 512 * sizeof(_Float16);
    float*     zp = (float*)d_ws;
    _Float16*  wf = (_Float16*)((char*)d_ws + ZP_BYTES);
    _Float16*  xt = (_Float16*)((char*)d_ws + ZP_BYTES + WF_BYTES);

    prep_kernel<<<dim3(4096 + 64), dim3(256), 0, stream>>>(
        x, h, fc_w, fc_b, w1, b1, w2, b2, w3, b3, wf, zp, xt);
    conv_mfma3_kernel<<<dim3(WW / 16, HH / 16, BB), dim3(256), 0, stream>>>(
        xt, wf, bias, zp, out);
}